// Round 10
// baseline (337.289 us; speedup 1.0000x reference)
//
#include <hip/hip_runtime.h>
#include <hip/hip_cooperative_groups.h>
#include <stdint.h>

namespace cg = cooperative_groups;

// GraphConv: out = indeg^-1/2 * segsum_dst( (feat * outdeg^-1/2)[src] ) @ W
// R15: ONE persistent cooperative kernel (hipLaunchCooperativeKernel),
// 4 phases split by grid.sync():
//   P0 zero counters (replaces memset dispatch)
//   P1 part chunks (static, b<241; R13 2048-bin dual bucketing -> BK=64
//      pairs) || gemm tiles via atomic-ticket queue (idle blocks stream
//      tiles while part blocks crunch)
//   P2 deg -> oscale (782 src buckets strided)
//   P3 aggp BK=64 via ticket queue: perfect balance, 16 sustained waves/CU
// Removes ~all inter-dispatch gaps + memset; aggp/part/gemm/deg bodies are
// the R13-proven ones (absmax path identical: per-edge oscale in aggp).

#define DIM 128
#define BK 64             // nodes per dst bucket
#define MAXB 2048         // >= NPB = ceil(100000/64) = 1563
#define CAPB 1280         // edges per dst bucket (mean 1024, +8 sigma)
#define SK 128            // nodes per src bucket (degree only)
#define MAXS 1024         // >= NPS = 782
#define CAPS 2560         // edges per src bucket
#define PT 512            // threads per block
#define EPT 13            // edges per thread in part phase
#define CHUNK (PT * EPT)  // 6656 edges per part chunk

typedef unsigned int uint;
typedef unsigned short ushortT;
typedef __attribute__((ext_vector_type(8))) _Float16 f16x8;
typedef __attribute__((ext_vector_type(4))) float f32x4;

__device__ __forceinline__ ushortT f2bf(float x) {
    uint u = __float_as_uint(x);
    u = (u + 0x7FFFu + ((u >> 16) & 1u)) >> 16;   // RNE
    return (ushortT)u;
}
__device__ __forceinline__ float bflo(uint u) { return __uint_as_float(u << 16); }
__device__ __forceinline__ float bfhi(uint u) { return __uint_as_float(u & 0xffff0000u); }

union H16 { _Float16 h; ushortT u; };
__device__ __forceinline__ ushortT f2h_bits(float x) {
    H16 t; t.h = (_Float16)x; return t.u;
}

// LDS union byte offsets (part phase is the max: 71232B).
#define OFF_CD    0        // int[2048]
#define OFF_LOFD  8192     // int[2048]
#define OFF_CS    16384    // int[1024]
#define OFF_LOFS  20480    // int[1024]
#define OFF_BUFD  24576    // int[CHUNK]
#define OFF_BUFB  51200    // ushort[CHUNK]
#define OFF_BUFS  64512    // uchar[CHUNK]
#define OFF_WTOT  71168    // int[16]
#define SMEM_SZ   71232
// aggp phase layout (within smem): raw 0..5120, sorted 5120..10240,
// hist 10240, offs 10496, cur 10752 (bytes).

__global__ __launch_bounds__(PT) void mega(
    const int* __restrict__ src, const int* __restrict__ dst,
    int* __restrict__ curB, int* __restrict__ curS, int* __restrict__ ctrs,
    int* __restrict__ pairs, unsigned char* __restrict__ srcb,
    const float* __restrict__ feat, const float* __restrict__ W,
    ushortT* __restrict__ h, float* __restrict__ oscale,
    float* __restrict__ out,
    int E, int N, int NPB, int NPS, int NPART, int NGEMM) {
    cg::grid_group gg = cg::this_grid();
    __shared__ __align__(16) unsigned char smem[SMEM_SZ];
    __shared__ int tkt;

    int b = blockIdx.x, tid = threadIdx.x, GD = gridDim.x;

    // ---------------- phase 0: zero curB + curS + ctrs (contiguous) --------
    int ztot = NPB + NPS + 2;
    for (int i = b * PT + tid; i < ztot; i += GD * PT) curB[i] = 0;
    gg.sync();

    // ---------------- phase 1a: part chunks (static: chunk c = b) ----------
    for (int c = b; c < NPART; c += GD) {
        int* cD = (int*)(smem + OFF_CD);          // becomes global base
        int* lofD = (int*)(smem + OFF_LOFD);
        int* cS = (int*)(smem + OFF_CS);          // becomes global base
        int* lofS = (int*)(smem + OFF_LOFS);
        int* bufD = (int*)(smem + OFF_BUFD);
        ushortT* bufB = (ushortT*)(smem + OFF_BUFB);
        unsigned char* bufS = (unsigned char*)(smem + OFF_BUFS);
        int* wtotD = (int*)(smem + OFF_WTOT);
        int* wtotS = wtotD + 8;

        long long base = (long long)c * CHUNK;
        for (int i = tid; i < MAXB; i += PT) cD[i] = 0;
        for (int i = tid; i < MAXS; i += PT) cS[i] = 0;
        __syncthreads();

        // P1: count both axes; atomicAdd return = unique local rank.
        int sv[EPT], dv[EPT], lrD[EPT], lrS[EPT];
#pragma unroll
        for (int j = 0; j < EPT; ++j) {
            long long e = base + tid + j * PT;
            bool ok = e < E;
            int s = 0, d = 0;
            if (ok) { s = src[e]; d = dst[e]; }
            sv[j] = s; dv[j] = d;
            lrD[j] = ok ? atomicAdd(&cD[d >> 6], 1) : 0;
            lrS[j] = ok ? atomicAdd(&cS[s >> 7], 1) : 0;
        }
        __syncthreads();

        // P2: blocked exclusive scans (dst 2048: 4/thread; src 1024: 2/thread)
        {
            int lane = tid & 63, wv = tid >> 6;
            int b0 = tid << 2;
            int s0 = cD[b0], s1 = cD[b0 + 1], s2 = cD[b0 + 2], s3 = cD[b0 + 3];
            int tsum = s0 + s1 + s2 + s3;
            int incl = tsum;
            for (int o = 1; o < 64; o <<= 1) {
                int y = __shfl_up(incl, o, 64);
                if (lane >= o) incl += y;
            }
            if (lane == 63) wtotD[wv] = incl;

            int a0idx = tid << 1;
            int t0 = cS[a0idx], t1 = cS[a0idx + 1];
            int ssum = t0 + t1;
            int sincl = ssum;
            for (int o = 1; o < 64; o <<= 1) {
                int y = __shfl_up(sincl, o, 64);
                if (lane >= o) sincl += y;
            }
            if (lane == 63) wtotS[wv] = sincl;
            __syncthreads();

            int wbD = 0, wbS = 0;
            for (int x = 0; x < wv; ++x) { wbD += wtotD[x]; wbS += wtotS[x]; }
            int exD = wbD + incl - tsum;
            lofD[b0] = exD;
            lofD[b0 + 1] = exD + s0;
            lofD[b0 + 2] = exD + s0 + s1;
            lofD[b0 + 3] = exD + s0 + s1 + s2;
            int exS = wbS + sincl - ssum;
            lofS[a0idx] = exS;
            lofS[a0idx + 1] = exS + t0;
        }
        __syncthreads();   // scans complete -> safe to overwrite cD/cS

        // P2b: bulk global reservations; overwrite cD/cS with global bases
        for (int i = tid; i < NPB; i += PT) {
            int cc = cD[i];
            cD[i] = cc ? atomicAdd(&curB[i], cc) : 0;
        }
        for (int i = tid; i < NPS; i += PT) {
            int cc = cS[i];
            cS[i] = cc ? atomicAdd(&curS[i], cc) : 0;
        }

        // P3: place edges into LDS at sorted positions (no atomics)
#pragma unroll
        for (int j = 0; j < EPT; ++j) {
            long long e = base + tid + j * PT;
            if (e < E) {
                int bb = dv[j] >> 6;
                int pos = lofD[bb] + lrD[j];
                bufD[pos] = (sv[j] << 6) | (dv[j] & 63);
                bufB[pos] = (ushortT)bb;
                bufS[lofS[sv[j] >> 7] + lrS[j]] = (unsigned char)(sv[j] & 127);
            }
        }
        __syncthreads();

        // P4-dst: search-free coalesced flush (bucket id from bufB)
        int cntE = (int)(((long long)E - base < (long long)CHUNK) ? (E - base) : CHUNK);
        for (int i = tid; i < cntE; i += PT) {
            int bb = bufB[i];
            int pos = cD[bb] + (i - lofD[bb]);
            if (pos < CAPB) pairs[(size_t)bb * CAPB + pos] = bufD[i];
        }
        // P4-src: binary search over lofS (10 steps)
        for (int i = tid; i < cntE; i += PT) {
            int lo = 0, hi = NPS - 1;
            while (lo < hi) { int mid = (lo + hi + 1) >> 1; if (lofS[mid] <= i) lo = mid; else hi = mid - 1; }
            int pos = cS[lo] + (i - lofS[lo]);
            if (pos < CAPS) srcb[(size_t)lo * CAPS + pos] = bufS[i];
        }
        __syncthreads();
    }

    // ---------------- phase 1b: gemm tiles via atomic ticket ---------------
    for (;;) {
        __syncthreads();
        if (tid == 0) tkt = atomicAdd(&ctrs[0], 1);
        __syncthreads();
        int t = tkt;
        if (t >= NGEMM) break;

        ushortT* Bs = (ushortT*)smem;   // 128*128 f16, XOR-swizzled (32KB)
        // stage + convert W[k][n] -> Bs; elem (n,k) at
        // n*128 + ((k>>3 ^ (n&7))<<3) + (k&7). 512 thr: k-pair x 16-n strip.
        {
            int kk = (tid >> 3) << 1;          // 0,2,...,126
            int n0 = (tid & 7) << 4;           // 0,16,...,112
            const float* w0 = &W[(size_t)kk * DIM + n0];
            const float* w1 = w0 + DIM;
#pragma unroll
            for (int jj = 0; jj < 4; ++jj) {
                float4 a = *(const float4*)&w0[jj * 4];
                float4 bq = *(const float4*)&w1[jj * 4];
                float av[4] = {a.x, a.y, a.z, a.w};
                float bv[4] = {bq.x, bq.y, bq.z, bq.w};
#pragma unroll
                for (int u = 0; u < 4; ++u) {
                    int n = n0 + jj * 4 + u;
                    uint uu = (uint)f2h_bits(av[u]) | ((uint)f2h_bits(bv[u]) << 16);
                    int idx = n * 128 + (((kk >> 3) ^ (n & 7)) << 3) + (kk & 7);
                    *(uint*)&Bs[idx] = uu;
                }
            }
        }
        __syncthreads();

        int wid = tid >> 6;       // 0..7 -> 8 m-tiles of 16 rows
        int l = tid & 63;
        int lr = l & 15;          // A row lane / B col lane
        int lk = l >> 4;          // k-group (8 consecutive k each)
        int m0 = t * 128;
        int row = m0 + wid * 16 + lr;
        int rr = (row < N) ? row : 0;
        const float* fp = feat + (size_t)rr * DIM;

        f32x4 acc[8];
        f32x4 z = {0.f, 0.f, 0.f, 0.f};
#pragma unroll
        for (int n = 0; n < 8; ++n) acc[n] = z;

#pragma unroll
        for (int kc = 0; kc < 4; ++kc) {
            int kb = kc * 32 + lk * 8;
            float4 x0 = *(const float4*)&fp[kb];
            float4 x1 = *(const float4*)&fp[kb + 4];
            float f[8] = {x0.x, x0.y, x0.z, x0.w, x1.x, x1.y, x1.z, x1.w};
            f16x8 ah, al;
#pragma unroll
            for (int j = 0; j < 8; ++j) {
                _Float16 hi = (_Float16)f[j];
                ah[j] = hi;
                al[j] = (_Float16)(f[j] - (float)hi);
            }
#pragma unroll
            for (int n = 0; n < 8; ++n) {
                int brow = n * 16 + lr;
                int bidx = brow * 128 + (kb ^ ((brow & 7) << 3));
                f16x8 bb = *(const f16x8*)&Bs[bidx];
                acc[n] = __builtin_amdgcn_mfma_f32_16x16x32_f16(ah, bb, acc[n], 0, 0, 0);
                acc[n] = __builtin_amdgcn_mfma_f32_16x16x32_f16(al, bb, acc[n], 0, 0, 0);
            }
        }

        // store: D row = lk*4+r, D col = n*16+lr; h pos 8c+n with c=lr.
#pragma unroll
        for (int r = 0; r < 4; ++r) {
            int ro = m0 + wid * 16 + lk * 4 + r;
            if (ro < N) {
                uint w0 = (uint)f2bf(acc[0][r]) | ((uint)f2bf(acc[1][r]) << 16);
                uint w1 = (uint)f2bf(acc[2][r]) | ((uint)f2bf(acc[3][r]) << 16);
                uint w2 = (uint)f2bf(acc[4][r]) | ((uint)f2bf(acc[5][r]) << 16);
                uint w3 = (uint)f2bf(acc[6][r]) | ((uint)f2bf(acc[7][r]) << 16);
                uint4 o = make_uint4(w0, w1, w2, w3);
                *(uint4*)&h[(size_t)ro * DIM + (lr << 3)] = o;
            }
        }
    }
    gg.sync();

    // ---------------- phase 2: deg -> oscale (strided buckets) -------------
    for (int p = b; p < NPS; p += GD) {
        int* hist = (int*)smem;   // 128 ints
        if (tid < SK) hist[tid] = 0;
        __syncthreads();
        int cnt = min(curS[p], CAPS);
        const unsigned char* bb = &srcb[(size_t)p * CAPS];
        for (int i = tid; i < cnt; i += PT) atomicAdd(&hist[bb[i]], 1);
        __syncthreads();
        if (tid < SK) {
            int node = p * SK + tid;
            if (node < N) oscale[node] = rsqrtf((float)max(hist[tid], 1));
        }
        __syncthreads();
    }
    gg.sync();

    // ---------------- phase 3: aggp BK=64 via atomic ticket ---------------
    for (;;) {
        __syncthreads();
        if (tid == 0) tkt = atomicAdd(&ctrs[1], 1);
        __syncthreads();
        int p = tkt;
        if (p >= NPB) break;

        int* raw = (int*)smem;                    // 1280
        int* sorted = (int*)(smem + 5120);        // 1280
        int* hist = (int*)(smem + 10240);         // 64
        int* offs = (int*)(smem + 10496);         // 64
        int* cur = (int*)(smem + 10752);          // 64

        if (tid < 64) hist[tid] = 0;
        __syncthreads();
        int cnt = min(curB[p], CAPB);
        const int* pb = &pairs[(size_t)p * CAPB];
        for (int i = tid; i < cnt; i += PT) {
            int w = pb[i];
            raw[i] = w;
            atomicAdd(&hist[w & 63], 1);
        }
        __syncthreads();
        if (tid < 64) {   // wave 0: 64-lane shuffle scan
            int x = hist[tid], incl = x;
            for (int o = 1; o < 64; o <<= 1) {
                int y = __shfl_up(incl, o, 64);
                if (tid >= o) incl += y;
            }
            offs[tid] = incl - x;
            cur[tid] = incl - x;
        }
        __syncthreads();
        for (int i = tid; i < cnt; i += PT) {
            int w = raw[i];
            int slot = atomicAdd(&cur[w & 63], 1);
            sorted[slot] = w >> 6;       // slot < cnt <= CAPB
        }
        __syncthreads();
        int g = tid >> 4, c = tid & 15;
        int cb = c << 3;
        for (int nd = g; nd < 64; nd += 32) {
            int node = p * BK + nd;
            if (node >= N) continue;
            int start = offs[nd];
            int degn = hist[nd];
            int end = min(start + degn, CAPB);
            float a0 = 0.f, a1 = 0.f, a2 = 0.f, a3 = 0.f;
            float a4 = 0.f, a5 = 0.f, a6 = 0.f, a7 = 0.f;
            int e = start;
            for (; e + 8 <= end; e += 8) {
                int s0 = sorted[e],     s1 = sorted[e + 1];
                int s2 = sorted[e + 2], s3 = sorted[e + 3];
                int s4 = sorted[e + 4], s5 = sorted[e + 5];
                int s6 = sorted[e + 6], s7 = sorted[e + 7];
                float o0 = oscale[s0], o1 = oscale[s1], o2 = oscale[s2], o3 = oscale[s3];
                float o4 = oscale[s4], o5 = oscale[s5], o6 = oscale[s6], o7 = oscale[s7];
                uint4 v0 = *(const uint4*)&h[(size_t)s0 * DIM + cb];
                uint4 v1 = *(const uint4*)&h[(size_t)s1 * DIM + cb];
                uint4 v2 = *(const uint4*)&h[(size_t)s2 * DIM + cb];
                uint4 v3 = *(const uint4*)&h[(size_t)s3 * DIM + cb];
                uint4 v4 = *(const uint4*)&h[(size_t)s4 * DIM + cb];
                uint4 v5 = *(const uint4*)&h[(size_t)s5 * DIM + cb];
                uint4 v6 = *(const uint4*)&h[(size_t)s6 * DIM + cb];
                uint4 v7 = *(const uint4*)&h[(size_t)s7 * DIM + cb];
                a0 += ((o0 * bflo(v0.x) + o1 * bflo(v1.x)) + (o2 * bflo(v2.x) + o3 * bflo(v3.x))) +
                      ((o4 * bflo(v4.x) + o5 * bflo(v5.x)) + (o6 * bflo(v6.x) + o7 * bflo(v7.x)));
                a1 += ((o0 * bfhi(v0.x) + o1 * bfhi(v1.x)) + (o2 * bfhi(v2.x) + o3 * bfhi(v3.x))) +
                      ((o4 * bfhi(v4.x) + o5 * bfhi(v5.x)) + (o6 * bfhi(v6.x) + o7 * bfhi(v7.x)));
                a2 += ((o0 * bflo(v0.y) + o1 * bflo(v1.y)) + (o2 * bflo(v2.y) + o3 * bflo(v3.y))) +
                      ((o4 * bflo(v4.y) + o5 * bflo(v5.y)) + (o6 * bflo(v6.y) + o7 * bflo(v7.y)));
                a3 += ((o0 * bfhi(v0.y) + o1 * bfhi(v1.y)) + (o2 * bfhi(v2.y) + o3 * bfhi(v3.y))) +
                      ((o4 * bfhi(v4.y) + o5 * bfhi(v5.y)) + (o6 * bfhi(v6.y) + o7 * bfhi(v7.y)));
                a4 += ((o0 * bflo(v0.z) + o1 * bflo(v1.z)) + (o2 * bflo(v2.z) + o3 * bflo(v3.z))) +
                      ((o4 * bflo(v4.z) + o5 * bflo(v5.z)) + (o6 * bflo(v6.z) + o7 * bflo(v7.z)));
                a5 += ((o0 * bfhi(v0.z) + o1 * bfhi(v1.z)) + (o2 * bfhi(v2.z) + o3 * bfhi(v3.z))) +
                      ((o4 * bfhi(v4.z) + o5 * bfhi(v5.z)) + (o6 * bfhi(v6.z) + o7 * bfhi(v7.z)));
                a6 += ((o0 * bflo(v0.w) + o1 * bflo(v1.w)) + (o2 * bflo(v2.w) + o3 * bflo(v3.w))) +
                      ((o4 * bflo(v4.w) + o5 * bflo(v5.w)) + (o6 * bflo(v6.w) + o7 * bflo(v7.w)));
                a7 += ((o0 * bfhi(v0.w) + o1 * bfhi(v1.w)) + (o2 * bfhi(v2.w) + o3 * bfhi(v3.w))) +
                      ((o4 * bfhi(v4.w) + o5 * bfhi(v5.w)) + (o6 * bfhi(v6.w) + o7 * bfhi(v7.w)));
            }
            for (; e < end; ++e) {
                int se = sorted[e];
                float os = oscale[se];
                uint4 v = *(const uint4*)&h[(size_t)se * DIM + cb];
                a0 += os * bflo(v.x); a1 += os * bfhi(v.x);
                a2 += os * bflo(v.y); a3 += os * bfhi(v.y);
                a4 += os * bflo(v.z); a5 += os * bfhi(v.z);
                a6 += os * bflo(v.w); a7 += os * bfhi(v.w);
            }
            float scn = rsqrtf((float)max(degn, 1));
            size_t ob = (size_t)node * DIM + c;     // col = n*16 + c
            out[ob]       = a0 * scn;
            out[ob + 16]  = a1 * scn;
            out[ob + 32]  = a2 * scn;
            out[ob + 48]  = a3 * scn;
            out[ob + 64]  = a4 * scn;
            out[ob + 80]  = a5 * scn;
            out[ob + 96]  = a6 * scn;
            out[ob + 112] = a7 * scn;
        }
    }
}

extern "C" void kernel_launch(void* const* d_in, const int* in_sizes, int n_in,
                              void* d_out, int out_size, void* d_ws, size_t ws_size,
                              hipStream_t stream) {
    const int* src  = (const int*)d_in[2];
    const int* dst  = (const int*)d_in[3];
    const float* feat = (const float*)d_in[0];
    const float* W    = (const float*)d_in[1];
    float* out = (float*)d_out;

    int N = in_sizes[0] / DIM;        // 100000
    int E = in_sizes[2];              // 1.6M
    int NPB = (N + BK - 1) / BK;      // 1563 (<= MAXB)
    int NPS = (N + SK - 1) / SK;      // 782  (<= MAXS)
    int NPART = (E + CHUNK - 1) / CHUNK;   // 241
    int NGEMM = (N + 127) / 128;           // 782

    // workspace layout (curB, curS, ctrs contiguous for phase-0 zeroing)
    int* curB = (int*)d_ws;                       // NPB
    int* curS = curB + NPB;                       // NPS
    int* ctrs = curS + NPS;                       // 2 (gemm ticket, aggp ticket)
    float* oscale = (float*)(ctrs + 2);           // N
    int* pairs = (int*)(oscale + N);              // NPB*CAPB
    unsigned char* srcb = (unsigned char*)(pairs + (size_t)NPB * CAPB);  // NPS*CAPS
    uintptr_t hp = (uintptr_t)(srcb + (size_t)NPS * CAPS);
    ushortT* h = (ushortT*)((hp + 15) & ~(uintptr_t)15);  // N*DIM bf16

    int bpc = 0;
    hipOccupancyMaxActiveBlocksPerMultiprocessor(&bpc, mega, PT, 0);
    if (bpc < 1) bpc = 1;
    if (bpc > 2) bpc = 2;
    int grid = bpc * 256;

    void* args[] = {
        (void*)&src, (void*)&dst, (void*)&curB, (void*)&curS, (void*)&ctrs,
        (void*)&pairs, (void*)&srcb, (void*)&feat, (void*)&W, (void*)&h,
        (void*)&oscale, (void*)&out,
        (void*)&E, (void*)&N, (void*)&NPB, (void*)&NPS, (void*)&NPART, (void*)&NGEMM};
    hipLaunchCooperativeKernel((void*)mega, dim3(grid), dim3(PT), args, 0, stream);
}